// Round 3
// baseline (530.472 us; speedup 1.0000x reference)
//
#include <hip/hip_runtime.h>

typedef _Float16 half8   __attribute__((ext_vector_type(8)));
typedef __fp16   half2_t __attribute__((ext_vector_type(2)));
typedef float    floatx4 __attribute__((ext_vector_type(4)));

// ---------------------------------------------------------------------------
// Kernel 1: sort each (n,c) 1024-vector descending, write fp16 to workspace.
// One wave per vector, 16 elems/lane, register bitonic (unchanged).
// ws layout: z[c][n][x], row = c*256 + n
// ---------------------------------------------------------------------------
__global__ __launch_bounds__(256) void sort_kernel(const float* __restrict__ x,
                                                   unsigned short* __restrict__ zs) {
  const int wave = threadIdx.x >> 6;
  const int lane = threadIdx.x & 63;
  const int vec  = (blockIdx.x << 2) + wave;     // vec = n*64 + c

  const float* src = x + ((size_t)vec << 10) + (lane << 4);
  float v[16];
#pragma unroll
  for (int r4 = 0; r4 < 4; ++r4) {
    float4 f = *reinterpret_cast<const float4*>(src + (r4 << 2));
    v[r4 * 4 + 0] = f.x; v[r4 * 4 + 1] = f.y;
    v[r4 * 4 + 2] = f.z; v[r4 * 4 + 3] = f.w;
  }

  auto CEs = [&](int a, int b, bool desc) {
    float lo = fminf(v[a], v[b]);
    float hi = fmaxf(v[a], v[b]);
    v[a] = desc ? hi : lo;
    v[b] = desc ? lo : hi;
  };

#pragma unroll
  for (int r = 0; r < 16; r += 2) CEs(r, r + 1, (r & 2) == 0);
#pragma unroll
  for (int r = 0; r < 16; ++r) if ((r & 2) == 0) CEs(r, r | 2, (r & 4) == 0);
#pragma unroll
  for (int r = 0; r < 16; r += 2) CEs(r, r + 1, (r & 4) == 0);
#pragma unroll
  for (int r = 0; r < 16; ++r) if ((r & 4) == 0) CEs(r, r | 4, (r & 8) == 0);
#pragma unroll
  for (int r = 0; r < 16; ++r) if ((r & 2) == 0) CEs(r, r | 2, (r & 8) == 0);
#pragma unroll
  for (int r = 0; r < 16; r += 2) CEs(r, r + 1, (r & 8) == 0);

#pragma unroll
  for (int k = 16; k <= 1024; k <<= 1) {
    const bool d = (lane & (k >> 4)) == 0;
#pragma unroll
    for (int j = k >> 1; j >= 16; j >>= 1) {
      const int dl = j >> 4;
      const bool keepmax = (((lane & dl) == 0) == d);
#pragma unroll
      for (int r = 0; r < 16; ++r) {
        float p = __shfl_xor(v[r], dl, 64);
        v[r] = keepmax ? fmaxf(v[r], p) : fminf(v[r], p);
      }
    }
#pragma unroll
    for (int j = 8; j >= 1; j >>= 1)
#pragma unroll
      for (int r = 0; r < 16; ++r)
        if ((r & j) == 0) CEs(r, r | j, d);
  }

  const int n = vec >> 6, c = vec & 63;
  union { half2_t h2[8]; uint4 u[2]; } pk;
#pragma unroll
  for (int r = 0; r < 8; ++r)
    pk.h2[r] = __builtin_amdgcn_cvt_pkrtz(v[2 * r], v[2 * r + 1]);
  uint4* dst = reinterpret_cast<uint4*>(zs + ((size_t)(c * 256 + n) << 10) + (lane << 4));
  dst[0] = pk.u[0];
  dst[1] = pk.u[1];
}

// ---------------------------------------------------------------------------
// Kernel 2: W-stream-bound GEMM, redesigned.
// grid = 512 1-D blocks -> (c, nt) via XCD swizzle: each XCD owns 8 whole
// channels, so a channel's z (512KB) + its 8 column-slabs live in ONE L2.
// Block tile M=256 x N=128, BK=64; 4 waves (2M x 2N), wave tile 128x64.
// A (sorted z, fp16): NOT staged in LDS. z is L2/L3-resident; MFMA A-frags
//   are read directly from global as 16-row x 64B-line coalesced 16B loads.
// B (W, f32): reg-staged -> cvt_pkrtz fp16 -> LDS, DOUBLE-buffered (2x16KB),
//   chunk-XOR swizzle (ch ^= o&7), one __syncthreads per 64-K half-tile,
//   global loads for half-tile t+1 issued before computing half-tile t.
// 2 blocks/CU (launch_bounds(256,2), 32KB LDS) so cross-block wave overlap
// hides the barrier vmcnt drains.  W read exactly once from HBM (268 MB ->
// 42.6 us floor); total gemm floor ~58 us.
// ---------------------------------------------------------------------------
__global__ __launch_bounds__(256, 2) void gemm_kernel(const unsigned short* __restrict__ zs,
                                                      const float* __restrict__ W,
                                                      const float* __restrict__ bias,
                                                      float* __restrict__ out) {
  __shared__ __align__(16) _Float16 Bs[2][128 * 64];  // 2 x 16KB, [o][ch^(o&7)]

  const int bid = blockIdx.x;
  const int c   = ((bid & 7) << 3) | ((bid >> 3) & 7);  // channel (8 per XCD)
  const int nt  = bid >> 6;                             // 128-col slab, 0..7
  const int tid  = threadIdx.x;
  const int w = tid >> 6, lane = tid & 63;
  const int lr = lane & 15, q = lane >> 4;
  const int wm = w >> 1, wn = w & 1;

  const unsigned short* zc = zs + ((size_t)c << 18);                    // z[c][256][1024]
  const float*          wc = W + ((size_t)c << 20) + ((size_t)nt << 17); // 128 rows x 1024

  // B staging geometry: 4 passes x (256 thr covering 32 rows x 8 chunks of 32B)
  const int so = (w << 3) + (lane >> 3);   // row-in-pass-group 0..31
  const int sc = lane & 7;                 // 32B chunk (= one 16B fp16 chunk)
  // A frag per-lane row base: row = wm*128 + mi*16 + lr, k = kb + ks*32 + q*8
  const unsigned short* arow = zc + (((size_t)((wm << 7) + lr)) << 10) + (q << 3);

  floatx4 acc[8][4] = {};
  float4  breg[8];

  auto loadB = [&](int kb) {
#pragma unroll
    for (int p = 0; p < 4; ++p) {
      const int o = (p << 5) + so;
      const float* g = wc + ((size_t)o << 10) + kb + (sc << 3);
      breg[2 * p]     = *reinterpret_cast<const float4*>(g);
      breg[2 * p + 1] = *reinterpret_cast<const float4*>(g + 4);
    }
  };
  auto writeB = [&](int buf) {
#pragma unroll
    for (int p = 0; p < 4; ++p) {
      const int o = (p << 5) + so;
      union { half2_t h2[4]; half8 h8; } pk;
      const float4 f0 = breg[2 * p], f1 = breg[2 * p + 1];
      pk.h2[0] = __builtin_amdgcn_cvt_pkrtz(f0.x, f0.y);
      pk.h2[1] = __builtin_amdgcn_cvt_pkrtz(f0.z, f0.w);
      pk.h2[2] = __builtin_amdgcn_cvt_pkrtz(f1.x, f1.y);
      pk.h2[3] = __builtin_amdgcn_cvt_pkrtz(f1.z, f1.w);
      *reinterpret_cast<half8*>(&Bs[buf][(o << 6) + ((sc ^ (o & 7)) << 3)]) = pk.h8;
    }
  };
  auto compute = [&](int buf, int kb, int ks) {
    half8 af[8];
#pragma unroll
    for (int mi = 0; mi < 8; ++mi)
      af[mi] = *reinterpret_cast<const half8*>(arow + (mi << 14) + kb + (ks << 5));
#pragma unroll
    for (int ni = 0; ni < 4; ++ni) {
      const int o  = (wn << 6) + (ni << 4) + lr;
      const int ch = ((ks << 2) + q) ^ (o & 7);
      const half8 bf = *reinterpret_cast<const half8*>(&Bs[buf][(o << 6) + (ch << 3)]);
#pragma unroll
      for (int mi = 0; mi < 8; ++mi)
        acc[mi][ni] =
            __builtin_amdgcn_mfma_f32_16x16x32_f16(af[mi], bf, acc[mi][ni], 0, 0, 0);
    }
  };

  // prologue: stage k-tile 0 into buf0
  loadB(0);
  writeB(0);
  __syncthreads();

#pragma unroll 1
  for (int t = 0; t < 8; ++t) {
    const int kb = t << 7;
    loadB(kb + 64);                 // stage next half-tile (buf1) early
    compute(0, kb, 0);
    writeB(1);
    compute(0, kb, 1);
    __syncthreads();
    if (t < 7) loadB(kb + 128);     // stage next iteration's buf0 early
    compute(1, kb + 64, 0);
    if (t < 7) writeB(0);
    compute(1, kb + 64, 1);
    __syncthreads();
  }

  // epilogue: bias + sigmoid, out[n][c][o] fp32
#pragma unroll
  for (int ni = 0; ni < 4; ++ni) {
    const int col = (nt << 7) + (wn << 6) + (ni << 4) + lr;
    const float bv = bias[(c << 10) + col];
#pragma unroll
    for (int mi = 0; mi < 8; ++mi) {
      const int row0 = (wm << 7) + (mi << 4) + (q << 2);
#pragma unroll
      for (int rr = 0; rr < 4; ++rr) {
        const float y = acc[mi][ni][rr] + bv;
        const float s = __builtin_amdgcn_rcpf(1.0f + __expf(-y));
        out[((((size_t)(row0 + rr) << 6) | c) << 10) + col] = s;
      }
    }
  }
}

extern "C" void kernel_launch(void* const* d_in, const int* in_sizes, int n_in,
                              void* d_out, int out_size, void* d_ws, size_t ws_size,
                              hipStream_t stream) {
  const float* x    = (const float*)d_in[0];   // (256, 64, 32, 32) f32
  const float* W    = (const float*)d_in[1];   // (64, 1024, 1024) f32
  const float* bias = (const float*)d_in[2];   // (64, 1024) f32
  float*       out  = (float*)d_out;           // (256, 64, 1024) f32
  unsigned short* zs = (unsigned short*)d_ws;  // 16384*1024 fp16 = 33.5 MB

  sort_kernel<<<4096, 256, 0, stream>>>(x, zs);
  gemm_kernel<<<512, 256, 0, stream>>>(zs, W, bias, out);
}